// Round 1
// 78.396 us; speedup vs baseline: 1.0281x; 1.0281x over previous
//
#include <hip/hip_runtime.h>
#include <math.h>

#define BB 32
#define NN 2048
#define TB 256            // k1/k2a threads
#define QT 8              // queries per thread in k1 -> 2048 = NN per block
#define RCH 16            // ref chunks (split of the min over refs)
#define MCH (NN / RCH)    // 128 refs per chunk

// ws layout: part[RCH][2*BB][NN] f32 (8 MB) | partial[BB][8][7] f32 (7 KB)

__device__ __forceinline__ float wred(float v) {
#pragma unroll
    for (int o = 32; o > 0; o >>= 1) v += __shfl_down(v, o, 64);
    return v;
}

// K1: grid (1, BB, 2*RCH); blockIdx.z = rc*2 + role. 1024 blocks = 4/CU exact.
// Partial min over one 128-ref chunk for all 2048 queries of (b, role).
// Thread owns 8 CONTIGUOUS queries: loads = 6 coalesced dwordx4, stores = 2 dwordx4.
__global__ __launch_bounds__(TB) void k1_chamfer(
    const float* __restrict__ pred, const float* __restrict__ tgt,
    float* __restrict__ part)
{
    __shared__ float sa[MCH], sb[MCH], sc[MCH];

    const int tid  = threadIdx.x;
    const int b    = blockIdx.y;
    const int role = blockIdx.z & 1;
    const int rc   = blockIdx.z >> 1;

    const float* q = role ? tgt : pred;
    const float* r = role ? pred : tgt;

    // Query micro-panel first (independent of LDS stage; hides under barrier).
    const float* qb_ = q + (size_t)b * NN * 3;
    float f[24];
    const float4* qv = (const float4*)(qb_ + (size_t)tid * (QT * 3));
#pragma unroll
    for (int i = 0; i < 6; i++) ((float4*)f)[i] = qv[i];

    float px[QT], py[QT], mn[QT];
#pragma unroll
    for (int j = 0; j < QT; j++) {
        px[j] = f[3 * j + 0];
        py[j] = f[3 * j + 1];
        mn[j] = 3.4e38f;
    }

    // Stage refs in norm form; invisible refs poisoned far (d2 ~ 2e18).
    const float* rb = r + ((size_t)b * NN + (size_t)rc * MCH) * 3;
    if (tid < MCH) {
        float rx = rb[3 * tid + 0];
        float ry = rb[3 * tid + 1];
        float rv = rb[3 * tid + 2];
        if (rv != 1.0f) { rx = 1.0e9f; ry = 1.0e9f; }
        sa[tid] = -2.0f * rx;
        sb[tid] = -2.0f * ry;
        sc[tid] = fmaf(rx, rx, ry * ry);
    }
    __syncthreads();

    // 8 refs/iter: 6 uniform ds_read_b128 (broadcast, conflict-free),
    // per query 16 fma + 4 v_min3 -> 2.5 VALU/pair.
#pragma unroll 2
    for (int m = 0; m < MCH; m += 8) {
        float4 a0 = *(const float4*)&sa[m], a1 = *(const float4*)&sa[m + 4];
        float4 b0 = *(const float4*)&sb[m], b1 = *(const float4*)&sb[m + 4];
        float4 c0 = *(const float4*)&sc[m], c1 = *(const float4*)&sc[m + 4];
#pragma unroll
        for (int j = 0; j < QT; j++) {
            float s0 = fmaf(px[j], a0.x, fmaf(py[j], b0.x, c0.x));
            float s1 = fmaf(px[j], a0.y, fmaf(py[j], b0.y, c0.y));
            float s2 = fmaf(px[j], a0.z, fmaf(py[j], b0.z, c0.z));
            float s3 = fmaf(px[j], a0.w, fmaf(py[j], b0.w, c0.w));
            float s4 = fmaf(px[j], a1.x, fmaf(py[j], b1.x, c1.x));
            float s5 = fmaf(px[j], a1.y, fmaf(py[j], b1.y, c1.y));
            float s6 = fmaf(px[j], a1.z, fmaf(py[j], b1.z, c1.z));
            float s7 = fmaf(px[j], a1.w, fmaf(py[j], b1.w, c1.w));
            float u = fminf(fminf(s0, s1), s2);
            float v = fminf(fminf(s3, s4), s5);
            float w = fminf(fminf(s6, s7), mn[j]);
            mn[j] = fminf(fminf(u, v), w);
        }
    }

    float o[QT];
#pragma unroll
    for (int j = 0; j < QT; j++)
        o[j] = fmaf(px[j], px[j], py[j] * py[j]) + mn[j];

    float4* po = (float4*)&part[((size_t)rc * (2 * BB) + (size_t)role * BB + b) * NN
                                + (size_t)tid * QT];
    po[0] = make_float4(o[0], o[1], o[2], o[3]);
    po[1] = make_float4(o[4], o[5], o[6], o[7]);
}

// K2a: grid (NN/TB=8, BB) = 256 blocks (1/CU), 256 threads. Block (c,b) owns
// queries c*256..+256 of batch b, BOTH roles: combine 16 planes per query,
// sqrt+mask epilogue, block-reduce 7 sums -> partial[b][c][7]. No atomics.
__global__ __launch_bounds__(TB) void k2a_partial(
    const float* __restrict__ pred, const float* __restrict__ tgt,
    const float* __restrict__ smask, const float* __restrict__ part,
    float* __restrict__ partial)
{
    __shared__ float sred[7][4];
    const int tid = threadIdx.x;
    const int c   = blockIdx.x;
    const int b   = blockIdx.y;
    const int qi  = c * TB + tid;

    // role 0 (queries = pred): contrib_p, cnt_p, point/struct/mask sums
    float m0 = 3.4e38f, m1 = 3.4e38f;
#pragma unroll
    for (int k = 0; k < RCH; k++)
        m0 = fminf(m0, part[((size_t)k * (2 * BB) + b) * NN + qi]);
#pragma unroll
    for (int k = 0; k < RCH; k++)
        m1 = fminf(m1, part[((size_t)k * (2 * BB) + BB + b) * NN + qi]);

    const float* qp = pred + ((size_t)b * NN + qi) * 3;
    const float* tp = tgt  + ((size_t)b * NN + qi) * 3;
    const float2 sm = *(const float2*)&smask[((size_t)b * NN + qi) * 2];

    float pvf = (qp[2] == 1.0f) ? 1.0f : 0.0f;   // pred visible
    float vm  = (tp[2] == 1.0f) ? 1.0f : 0.0f;   // tgt visible

    float a0 = sqrtf(fmaxf(m0, 1e-12f)) * pvf;   // contrib_p
    float a1 = pvf;                              // cnt_p
    float dx = qp[0] - tp[0], dy = qp[1] - tp[1];
    float e2 = fmaf(dx, dx, dy * dy);
    float tm = fminf(fmaxf(sm.x + sm.y, 0.0f), 1.0f) * vm;
    float a2 = e2 * vm;                          // point sum
    float a3 = e2 * tm;                          // struct sum
    float a4 = tm;                               // mask sum (parity with ref)
    float a5 = sqrtf(fmaxf(m1, 1e-12f)) * vm;    // contrib_t (query = tgt)
    float a6 = vm;                               // cnt_t

    float v[7] = {a0, a1, a2, a3, a4, a5, a6};
    const int wave = tid >> 6, lane = tid & 63;
#pragma unroll
    for (int i = 0; i < 7; i++) {
        float rv = wred(v[i]);
        if (lane == 0) sred[i][wave] = rv;
    }
    __syncthreads();
    if (tid == 0) {
        float* dst = partial + ((size_t)b * 8 + c) * 7;
#pragma unroll
        for (int i = 0; i < 7; i++)
            dst[i] = sred[i][0] + sred[i][1] + sred[i][2] + sred[i][3];
    }
}

// K2b: 1 block, 64 threads. Lane b<32 combines its 8 chunk-partials, does the
// per-batch nonlinear chamfer math; wave-reduce the 3 linear terms; lane 0
// writes out[0..3] directly (no atomics, no pre-zeroing anywhere).
__global__ __launch_bounds__(64) void k2b_final(
    const float* __restrict__ partial, float* __restrict__ out)
{
    const int tid = threadIdx.x;
    float lp = 0.0f, lc = 0.0f, ls = 0.0f;
    if (tid < BB) {
        float s[7] = {0, 0, 0, 0, 0, 0, 0};
#pragma unroll
        for (int c = 0; c < 8; c++) {
            const float* src = partial + ((size_t)tid * 8 + c) * 7;
#pragma unroll
            for (int i = 0; i < 7; i++) s[i] += src[i];
        }
        float sp = s[0], cp = s[1], spt = s[2], sst = s[3];
        float st_ = s[5], ct = s[6];
        float mp = sp / fmaxf(cp, 1.0f);
        float mt = st_ / fmaxf(ct, 1.0f);
        float ch = (cp > 0.0f && ct > 0.0f) ? 0.5f * (mp + mt) : 0.0f;

        const float denom = (float)BB * (float)NN * 2.0f;
        lp = spt / denom;            // loss_point contribution (batch b)
        ls = sst / denom;            // loss_struct contribution
        lc = ch / (float)BB;         // loss_chamfer contribution
    }
    float t_lp = wred(lp);
    float t_lc = wred(lc);
    float t_ls = wred(ls);
    if (tid == 0) {
        out[0] = t_lp + 5.0f * t_lc + 2.0f * t_ls;
        out[1] = t_lp;
        out[2] = 0.0f;
        out[3] = t_lc;
    }
}

extern "C" void kernel_launch(void* const* d_in, const int* in_sizes, int n_in,
                              void* d_out, int out_size, void* d_ws, size_t ws_size,
                              hipStream_t stream)
{
    const float* pred  = (const float*)d_in[0];
    const float* tgt   = (const float*)d_in[1];
    const float* smask = (const float*)d_in[2];
    float* out = (float*)d_out;
    float* part = (float*)d_ws;                               // 8 MB
    float* partial = (float*)((char*)d_ws + (size_t)RCH * 2 * BB * NN * 4); // 7 KB

    k1_chamfer<<<dim3(1, BB, 2 * RCH), TB, 0, stream>>>(pred, tgt, part);
    k2a_partial<<<dim3(NN / TB, BB), TB, 0, stream>>>(pred, tgt, smask, part, partial);
    k2b_final<<<dim3(1), 64, 0, stream>>>(partial, out);
}